// Round 12
// baseline (267.740 us; speedup 1.0000x reference)
//
#include <hip/hip_runtime.h>
#include <hip/hip_bf16.h>

#define NN 25000
#define EE 200000
#define HH 64
#define LL 3
#define NB 98   // ceil(NN/256)
#define NCG 22

typedef __bf16 bf16x8 __attribute__((ext_vector_type(8)));
typedef float f32x4 __attribute__((ext_vector_type(4)));

__device__ __forceinline__ bf16x8 cvt8(float4 a, float4 b) {
    bf16x8 r;
    r[0] = (__bf16)a.x; r[1] = (__bf16)a.y; r[2] = (__bf16)a.z; r[3] = (__bf16)a.w;
    r[4] = (__bf16)b.x; r[5] = (__bf16)b.y; r[6] = (__bf16)b.z; r[7] = (__bf16)b.w;
    return r;
}

__device__ __forceinline__ bf16x8 cvt8a(const float* v) {
    bf16x8 r;
#pragma unroll
    for (int k = 0; k < 8; k++) r[k] = (__bf16)v[k];
    return r;
}

// packed B-fragment layout: [layer][cg(22)][cb(4)][lane(64)][8] bf16
// cg 0-5: [Wn_self;Wn_msg;Wn_edge]; cg 6-13: Wfc rows 0-255;
// cg 14-17: [We_self;We_nbr]; cg 18-19: Wse=We_self(l-1)@Wn_edge(l);
// cg 20-21: Wne=We_nbr(l-1)@Wn_edge(l)  (layers 1,2 only)
__device__ __forceinline__ bf16x8 load_bfrag(const __bf16* __restrict__ packw,
                                             int layer, int cg, int cb, int lane) {
    const __bf16* p = packw + ((((size_t)(layer * NCG + cg)) * 4 + cb) * 64 + lane) * 8;
    return *reinterpret_cast<const bf16x8*>(p);
}

__global__ void k_zero(int* __restrict__ p) {
    int i = blockIdx.x * 256 + threadIdx.x;
    if (i < NN) p[i] = 0;
}

__global__ void k_hist(const int* __restrict__ trg, int* __restrict__ count) {
    int e = blockIdx.x * 256 + threadIdx.x;
    if (e < EE) atomicAdd(&count[trg[e]], 1);
}

__global__ void __launch_bounds__(256) k_bsum(const int* __restrict__ count,
                                              int* __restrict__ btot) {
    int i = blockIdx.x * 256 + threadIdx.x;
    int v = (i < NN) ? count[i] : 0;
#pragma unroll
    for (int o = 1; o < 64; o <<= 1) v += __shfl_xor(v, o);
    __shared__ int l[4];
    if ((threadIdx.x & 63) == 0) l[threadIdx.x >> 6] = v;
    __syncthreads();
    if (threadIdx.x == 0) btot[blockIdx.x] = l[0] + l[1] + l[2] + l[3];
}

__global__ void k_bscan(const int* __restrict__ btot, int* __restrict__ bbase) {
    __shared__ int l[128];
    int t = threadIdx.x;
    int v = (t < NB) ? btot[t] : 0;
    l[t] = v;
    __syncthreads();
    for (int o = 1; o < 128; o <<= 1) {
        int u = (t >= o) ? l[t - o] : 0;
        __syncthreads();
        l[t] += u;
        __syncthreads();
    }
    if (t < NB) bbase[t] = l[t] - v;  // exclusive
}

__global__ void __launch_bounds__(256) k_apply(const int* __restrict__ count,
                                               const int* __restrict__ bbase,
                                               int* __restrict__ offs,
                                               int* __restrict__ cursor) {
    __shared__ int l[256];
    int t = threadIdx.x;
    int i = blockIdx.x * 256 + t;
    int v = (i < NN) ? count[i] : 0;
    l[t] = v;
    __syncthreads();
    for (int o = 1; o < 256; o <<= 1) {
        int u = (t >= o) ? l[t - o] : 0;
        __syncthreads();
        l[t] += u;
        __syncthreads();
    }
    int ex = bbase[blockIdx.x] + l[t] - v;
    if (i < NN) { offs[i] = ex; cursor[i] = ex; }
    if (i == NN - 1) offs[NN] = ex + v;
}

__global__ void k_fill(const int* __restrict__ trg, int* __restrict__ cursor,
                       int* __restrict__ inc) {
    int e = blockIdx.x * 256 + threadIdx.x;
    if (e < EE) {
        int pos = atomicAdd(&cursor[trg[e]], 1);
        inc[pos] = e;
    }
}

// Wse[l]=We_self[l-1]@Wn_edge[l], Wne[l]=We_nbr[l-1]@Wn_edge[l], ben[l]=be[l-1]@Wn_edge[l]
__global__ void k_matW(const float* __restrict__ We_self, const float* __restrict__ We_nbr,
                       const float* __restrict__ be, const float* __restrict__ Wn_edge,
                       float* __restrict__ Wse, float* __restrict__ Wne,
                       float* __restrict__ ben) {
    int idx = blockIdx.x * 256 + threadIdx.x;
    const int PER = 2 * HH * HH + HH;
    if (idx >= 2 * PER) return;
    int l = 1 + idx / PER;
    int r2 = idx % PER;
    const float* wn = Wn_edge + (size_t)l * HH * HH;
    float acc = 0.f;
    if (r2 < HH * HH) {
        int r = r2 >> 6, c = r2 & 63;
        const float* a = We_self + (size_t)(l - 1) * HH * HH + r * HH;
        for (int k = 0; k < HH; k++) acc += a[k] * wn[k * HH + c];
        Wse[(size_t)l * HH * HH + r2] = acc;
    } else if (r2 < 2 * HH * HH) {
        int q = r2 - HH * HH;
        int r = q >> 6, c = q & 63;
        const float* a = We_nbr + (size_t)(l - 1) * HH * HH + r * HH;
        for (int k = 0; k < HH; k++) acc += a[k] * wn[k * HH + c];
        Wne[(size_t)l * HH * HH + q] = acc;
    } else {
        int c = r2 - 2 * HH * HH;
        const float* a = be + (size_t)(l - 1) * HH;
        for (int k = 0; k < HH; k++) acc += a[k] * wn[k * HH + c];
        ben[l * HH + c] = acc;
    }
}

// pack weights into MFMA B-fragment layout (bf16)
__global__ void k_pack(const float* __restrict__ Wn_self, const float* __restrict__ Wn_msg,
                       const float* __restrict__ Wn_edge, const float* __restrict__ Wfc,
                       const float* __restrict__ We_self, const float* __restrict__ We_nbr,
                       const float* __restrict__ Wse, const float* __restrict__ Wne,
                       __bf16* __restrict__ packw) {
    int idx = blockIdx.x * 256 + threadIdx.x;
    if (idx >= 3 * NCG * 4 * 64 * 8) return;
    int i  = idx & 7;
    int l  = (idx >> 3) & 63;
    int cb = (idx >> 9) & 3;
    int cgl = idx >> 11;          // layer*NCG + cg
    int layer = cgl / NCG;
    int cg = cgl % NCG;
    int col = cb * 16 + (l & 15);
    int krow = 8 * (l >> 4) + i;  // within 32-row chunk
    const float* M;
    int row;
    if (cg < 6) {
        const float* mats[3] = {Wn_self, Wn_msg, Wn_edge};
        M = mats[cg >> 1] + (size_t)layer * HH * HH;
        row = (cg & 1) * 32 + krow;
    } else if (cg < 14) {
        M = Wfc + (size_t)layer * 257 * HH;
        row = (cg - 6) * 32 + krow;
    } else if (cg < 18) {
        M = (((cg - 14) >> 1) == 0 ? We_self : We_nbr) + (size_t)layer * HH * HH;
        row = ((cg - 14) & 1) * 32 + krow;
    } else {
        if (layer == 0) { packw[idx] = (__bf16)0.f; return; }
        M = (((cg - 18) >> 1) == 0 ? Wse : Wne) + (size_t)layer * HH * HH;
        row = ((cg - 18) & 1) * 32 + krow;
    }
    packw[idx] = (__bf16)M[(size_t)row * HH + col];
}

// layer 0 aggregation: gather f32 x_in (no relu) + f32 ef_in; outputs bf16
__global__ void __launch_bounds__(256) k_agg0(
        const float* __restrict__ x, const float* __restrict__ ef,
        const int* __restrict__ offs, const int* __restrict__ inc,
        __bf16* __restrict__ aggx, __bf16* __restrict__ agge) {
    int wave = threadIdx.x >> 6, lane = threadIdx.x & 63;
    int v = blockIdx.x * 4 + wave;
    int s = offs[v], en = offs[v + 1];
    int deg = en - s;
    int g = lane >> 3, t = lane & 7;
    float ax[8] = {0,0,0,0,0,0,0,0};
    float ae[8] = {0,0,0,0,0,0,0,0};
    if (deg > 0) {
        int dm1 = deg - 1;
        int idx = inc[s + (lane < deg ? lane : dm1)];
        int nblk = (deg + 7) >> 3;
        if (nblk > 8) nblk = 8;
        for (int b = 0; b < nblk; b++) {
            int j = b * 8 + g;
            int e0 = __shfl(idx, j < deg ? j : dm1);
            float w = (j < deg) ? 1.f : 0.f;
            const float* xr = x + (size_t)(e0 >> 3) * HH + t * 8;
            float4 x0 = *(const float4*)xr, x1 = *(const float4*)(xr + 4);
            const float* fr = ef + (size_t)e0 * HH + t * 8;
            float4 f0 = *(const float4*)fr, f1 = *(const float4*)(fr + 4);
            ax[0] += w * x0.x; ax[1] += w * x0.y; ax[2] += w * x0.z; ax[3] += w * x0.w;
            ax[4] += w * x1.x; ax[5] += w * x1.y; ax[6] += w * x1.z; ax[7] += w * x1.w;
            ae[0] += w * f0.x; ae[1] += w * f0.y; ae[2] += w * f0.z; ae[3] += w * f0.w;
            ae[4] += w * f1.x; ae[5] += w * f1.y; ae[6] += w * f1.z; ae[7] += w * f1.w;
        }
        for (int j = 64 + g; j < deg; j += 8) {
            int e0 = inc[s + j];
            const float* xr = x + (size_t)(e0 >> 3) * HH + t * 8;
            float4 x0 = *(const float4*)xr, x1 = *(const float4*)(xr + 4);
            const float* fr = ef + (size_t)e0 * HH + t * 8;
            float4 f0 = *(const float4*)fr, f1 = *(const float4*)(fr + 4);
            ax[0] += x0.x; ax[1] += x0.y; ax[2] += x0.z; ax[3] += x0.w;
            ax[4] += x1.x; ax[5] += x1.y; ax[6] += x1.z; ax[7] += x1.w;
            ae[0] += f0.x; ae[1] += f0.y; ae[2] += f0.z; ae[3] += f0.w;
            ae[4] += f1.x; ae[5] += f1.y; ae[6] += f1.z; ae[7] += f1.w;
        }
    }
#pragma unroll
    for (int k = 0; k < 8; k++) {
        ax[k] += __shfl_xor(ax[k], 8); ax[k] += __shfl_xor(ax[k], 16); ax[k] += __shfl_xor(ax[k], 32);
        ae[k] += __shfl_xor(ae[k], 8); ae[k] += __shfl_xor(ae[k], 16); ae[k] += __shfl_xor(ae[k], 32);
    }
    if (g == 0) {
        *(bf16x8*)(aggx + (size_t)v * HH + t * 8) = cvt8a(ax);
        *(bf16x8*)(agge + (size_t)v * HH + t * 8) = cvt8a(ae);
    }
}

// layers >=1 aggregation: gather bf16 relu(x) and bf16 AGG, both by source node
__global__ void __launch_bounds__(256) k_aggN(
        const __bf16* __restrict__ x, const __bf16* __restrict__ AGG,
        const int* __restrict__ offs, const int* __restrict__ inc,
        __bf16* __restrict__ aggx, __bf16* __restrict__ partB) {
    int wave = threadIdx.x >> 6, lane = threadIdx.x & 63;
    int v = blockIdx.x * 4 + wave;
    int s = offs[v], en = offs[v + 1];
    int deg = en - s;
    int g = lane >> 3, t = lane & 7;
    float ax[8] = {0,0,0,0,0,0,0,0};
    float pb[8] = {0,0,0,0,0,0,0,0};
    if (deg > 0) {
        int dm1 = deg - 1;
        int idx = inc[s + (lane < deg ? lane : dm1)];
        int nblk = (deg + 7) >> 3;
        if (nblk > 8) nblk = 8;
        for (int b = 0; b < nblk; b++) {
            int j = b * 8 + g;
            int e0 = __shfl(idx, j < deg ? j : dm1);
            float w = (j < deg) ? 1.f : 0.f;
            int u = e0 >> 3;
            bf16x8 xb = *(const bf16x8*)(x + (size_t)u * HH + t * 8);
            bf16x8 ab = *(const bf16x8*)(AGG + (size_t)u * HH + t * 8);
#pragma unroll
            for (int k = 0; k < 8; k++) {
                ax[k] += w * fmaxf((float)xb[k], 0.f);
                pb[k] += w * (float)ab[k];
            }
        }
        for (int j = 64 + g; j < deg; j += 8) {
            int e0 = inc[s + j];
            int u = e0 >> 3;
            bf16x8 xb = *(const bf16x8*)(x + (size_t)u * HH + t * 8);
            bf16x8 ab = *(const bf16x8*)(AGG + (size_t)u * HH + t * 8);
#pragma unroll
            for (int k = 0; k < 8; k++) {
                ax[k] += fmaxf((float)xb[k], 0.f);
                pb[k] += (float)ab[k];
            }
        }
    }
#pragma unroll
    for (int k = 0; k < 8; k++) {
        ax[k] += __shfl_xor(ax[k], 8); ax[k] += __shfl_xor(ax[k], 16); ax[k] += __shfl_xor(ax[k], 32);
        pb[k] += __shfl_xor(pb[k], 8); pb[k] += __shfl_xor(pb[k], 16); pb[k] += __shfl_xor(pb[k], 32);
    }
    if (g == 0) {
        *(bf16x8*)(aggx + (size_t)v * HH + t * 8)  = cvt8a(ax);
        *(bf16x8*)(partB + (size_t)v * HH + t * 8) = cvt8a(pb);
    }
}

// layer 0 node GEMM: x1 = [x_f32 | aggx | agge] @ cg0-5 + bn
__global__ void __launch_bounds__(256) k_node0(
        const float* __restrict__ xin, const __bf16* __restrict__ aggx,
        const __bf16* __restrict__ agge, const __bf16* __restrict__ packw,
        const float* __restrict__ bn, __bf16* __restrict__ xout) {
    int wave = threadIdx.x >> 6, lane = threadIdx.x & 63;
    int tile = blockIdx.x * 4 + wave;
    if (tile * 16 >= NN) return;
    int r16 = lane & 15, hi = lane >> 4;
    int row = tile * 16 + r16;
    int rowc = row < NN ? row : NN - 1;
    f32x4 acc[4] = {{0,0,0,0},{0,0,0,0},{0,0,0,0},{0,0,0,0}};
#pragma unroll
    for (int c = 0; c < 6; c++) {
        int seg = c >> 1;
        bf16x8 a;
        if (seg == 0) {
            const float4* p = (const float4*)(xin + (size_t)rowc * HH + (c & 1) * 32 + hi * 8);
            a = cvt8(p[0], p[1]);
        } else {
            const __bf16* base = (seg == 1 ? aggx : agge) + (size_t)rowc * HH;
            a = *(const bf16x8*)(base + (c & 1) * 32 + hi * 8);
        }
#pragma unroll
        for (int cb = 0; cb < 4; cb++) {
            bf16x8 b = load_bfrag(packw, 0, c, cb, lane);
            acc[cb] = __builtin_amdgcn_mfma_f32_16x16x32_bf16(a, b, acc[cb], 0, 0, 0);
        }
    }
#pragma unroll
    for (int cb = 0; cb < 4; cb++) {
        int col = cb * 16 + r16;
        float bias = bn[col];
#pragma unroll
        for (int r = 0; r < 4; r++) {
            int orow = tile * 16 + hi * 4 + r;
            if (orow < NN) xout[(size_t)orow * HH + col] = (__bf16)(acc[cb][r] + bias);
        }
    }
}

// layers >=1 node GEMM: x_{i+1} = [relu(x) | aggx | AGG | partB] @ [cg0-1;cg2-3;cg18-19;cg20-21]
//                                 + bn + deg*ben
__global__ void __launch_bounds__(256) k_nodeL(
        const __bf16* __restrict__ xin, const __bf16* __restrict__ aggx,
        const __bf16* __restrict__ AGG, const __bf16* __restrict__ partB,
        const int* __restrict__ count, const __bf16* __restrict__ packw,
        const float* __restrict__ bn, const float* __restrict__ ben,
        __bf16* __restrict__ xout, int layer) {
    int wave = threadIdx.x >> 6, lane = threadIdx.x & 63;
    int tile = blockIdx.x * 4 + wave;
    if (tile * 16 >= NN) return;
    int r16 = lane & 15, hi = lane >> 4;
    int row = tile * 16 + r16;
    int rowc = row < NN ? row : NN - 1;
    f32x4 acc[4] = {{0,0,0,0},{0,0,0,0},{0,0,0,0},{0,0,0,0}};
    const int cgmap[8] = {0, 1, 2, 3, 18, 19, 20, 21};
#pragma unroll
    for (int c = 0; c < 8; c++) {
        int seg = c >> 1;
        bf16x8 a;
        if (seg == 0) {
            bf16x8 v = *(const bf16x8*)(xin + (size_t)rowc * HH + (c & 1) * 32 + hi * 8);
#pragma unroll
            for (int k = 0; k < 8; k++) a[k] = (__bf16)fmaxf((float)v[k], 0.f);
        } else {
            const __bf16* base = (seg == 1 ? aggx : (seg == 2 ? AGG : partB)) + (size_t)rowc * HH;
            a = *(const bf16x8*)(base + (c & 1) * 32 + hi * 8);
        }
#pragma unroll
        for (int cb = 0; cb < 4; cb++) {
            bf16x8 b = load_bfrag(packw, layer, cgmap[c], cb, lane);
            acc[cb] = __builtin_amdgcn_mfma_f32_16x16x32_bf16(a, b, acc[cb], 0, 0, 0);
        }
    }
#pragma unroll
    for (int cb = 0; cb < 4; cb++) {
        int col = cb * 16 + r16;
        float bias = bn[layer * HH + col];
        float benc = ben[layer * HH + col];
#pragma unroll
        for (int r = 0; r < 4; r++) {
            int orow = tile * 16 + hi * 4 + r;
            if (orow < NN) {
                float dg = (float)count[orow];
                xout[(size_t)orow * HH + col] = (__bf16)(acc[cb][r] + bias + dg * benc);
            }
        }
    }
}

// ef_out(bf16) = [ef_in | xs | xt | |xs-xt| | sim] @ Wfc + bfc  (sim fused, 16 edges/wave)
template<bool EF32>
__global__ void __launch_bounds__(256) k_fc(
        const void* __restrict__ efp, const __bf16* __restrict__ xn,
        const int* __restrict__ trg, const __bf16* __restrict__ packw,
        const float* __restrict__ Wfc, const float* __restrict__ bfc,
        __bf16* __restrict__ efout, int layer) {
    const float*  eff = (const float*)efp;
    const __bf16* efh = (const __bf16*)efp;
    int wave = threadIdx.x >> 6, lane = threadIdx.x & 63;
    int tile = blockIdx.x * 4 + wave;
    int r16 = lane & 15, hi = lane >> 4;
    int e = tile * 16 + r16;
    int srcn = e >> 3;
    int tn = trg[e];
    f32x4 acc[4] = {{0,0,0,0},{0,0,0,0},{0,0,0,0},{0,0,0,0}};
    float xsv[16], xtv[16];
#pragma unroll
    for (int c = 0; c < 8; c++) {
        int half = c & 1;
        bf16x8 a;
        if (c < 2) {
            if constexpr (EF32) {
                const float4* p = (const float4*)(eff + (size_t)e * HH + half * 32 + hi * 8);
                a = cvt8(p[0], p[1]);
            } else {
                a = *(const bf16x8*)(efh + (size_t)e * HH + half * 32 + hi * 8);
            }
        } else if (c < 4) {
            a = *(const bf16x8*)(xn + (size_t)srcn * HH + half * 32 + hi * 8);
#pragma unroll
            for (int k = 0; k < 8; k++) xsv[half * 8 + k] = (float)a[k];
        } else if (c < 6) {
            a = *(const bf16x8*)(xn + (size_t)tn * HH + half * 32 + hi * 8);
#pragma unroll
            for (int k = 0; k < 8; k++) xtv[half * 8 + k] = (float)a[k];
        } else {
#pragma unroll
            for (int k = 0; k < 8; k++)
                a[k] = (__bf16)fabsf(xsv[half * 8 + k] - xtv[half * 8 + k]);
        }
#pragma unroll
        for (int cb = 0; cb < 4; cb++) {
            bf16x8 b = load_bfrag(packw, layer, 6 + c, cb, lane);
            acc[cb] = __builtin_amdgcn_mfma_f32_16x16x32_bf16(a, b, acc[cb], 0, 0, 0);
        }
    }
    float dp = 0.f, nx2 = 0.f, nt2 = 0.f;
#pragma unroll
    for (int j = 0; j < 16; j++) {
        dp  += xsv[j] * xtv[j];
        nx2 += xsv[j] * xsv[j];
        nt2 += xtv[j] * xtv[j];
    }
    dp  += __shfl_xor(dp, 16);  dp  += __shfl_xor(dp, 32);
    nx2 += __shfl_xor(nx2, 16); nx2 += __shfl_xor(nx2, 32);
    nt2 += __shfl_xor(nt2, 16); nt2 += __shfl_xor(nt2, 32);
    float sim = dp / fmaxf(sqrtf(nx2 * nt2), 1e-8f);
    float simr[4];
#pragma unroll
    for (int r = 0; r < 4; r++) simr[r] = __shfl(sim, hi * 4 + r);
    const float* wlast = Wfc + ((size_t)layer * 257 + 256) * HH;  // row 256 (sim)
#pragma unroll
    for (int cb = 0; cb < 4; cb++) {
        int col = cb * 16 + r16;
        float wl = wlast[col];
        float bias = bfc[layer * HH + col];
#pragma unroll
        for (int r = 0; r < 4; r++) {
            efout[(size_t)(tile * 16 + hi * 4 + r) * HH + col] =
                (__bf16)(acc[cb][r] + simr[r] * wl + bias);
        }
    }
}

// phase 1: aggregate incoming efc for the block's 8 source nodes into LDS
//          (+ optionally spill AGG to global for the next layer)
// phase 2: edge_out = [efc | AGG_lds[e>>3]] @ [We_self;We_nbr] + be
template<int LAST, int WAGG>
__global__ void __launch_bounds__(256) k_edgeout(
        const __bf16* __restrict__ efc, const int* __restrict__ offs,
        const int* __restrict__ inc, const __bf16* __restrict__ packw,
        const float* __restrict__ be, __bf16* __restrict__ out16,
        float* __restrict__ out32, __bf16* __restrict__ AGGout, int layer) {
    __shared__ float aggl[8][HH];
    int wave = threadIdx.x >> 6, lane = threadIdx.x & 63;
    int g = lane >> 3, t = lane & 7;
#pragma unroll
    for (int q = 0; q < 2; q++) {
        int vloc = wave * 2 + q;
        int v = blockIdx.x * 8 + vloc;
        int s = offs[v], en = offs[v + 1];
        int deg = en - s;
        float a[8] = {0,0,0,0,0,0,0,0};
        if (deg > 0) {
            int dm1 = deg - 1;
            int idx = inc[s + (lane < deg ? lane : dm1)];
            int nblk = (deg + 7) >> 3;
            if (nblk > 8) nblk = 8;
            for (int b = 0; b < nblk; b++) {
                int j = b * 8 + g;
                int e0 = __shfl(idx, j < deg ? j : dm1);
                float w = (j < deg) ? 1.f : 0.f;
                bf16x8 f = *(const bf16x8*)(efc + (size_t)e0 * HH + t * 8);
#pragma unroll
                for (int k = 0; k < 8; k++) a[k] += w * (float)f[k];
            }
            for (int j = 64 + g; j < deg; j += 8) {
                int e0 = inc[s + j];
                bf16x8 f = *(const bf16x8*)(efc + (size_t)e0 * HH + t * 8);
#pragma unroll
                for (int k = 0; k < 8; k++) a[k] += (float)f[k];
            }
        }
#pragma unroll
        for (int k = 0; k < 8; k++) {
            a[k] += __shfl_xor(a[k], 8);
            a[k] += __shfl_xor(a[k], 16);
            a[k] += __shfl_xor(a[k], 32);
        }
        if (g == 0) {
            *(float4*)&aggl[vloc][t * 8]     = make_float4(a[0], a[1], a[2], a[3]);
            *(float4*)&aggl[vloc][t * 8 + 4] = make_float4(a[4], a[5], a[6], a[7]);
            if (WAGG) *(bf16x8*)(AGGout + (size_t)v * HH + t * 8) = cvt8a(a);
        }
    }
    __syncthreads();
    int tile = blockIdx.x * 4 + wave;
    int r16 = lane & 15, hi = lane >> 4;
    int e = tile * 16 + r16;
    f32x4 acc[4] = {{0,0,0,0},{0,0,0,0},{0,0,0,0},{0,0,0,0}};
#pragma unroll
    for (int c = 0; c < 4; c++) {
        bf16x8 a;
        if (c < 2) {
            a = *(const bf16x8*)(efc + (size_t)e * HH + (c & 1) * 32 + hi * 8);
        } else {
            int vloc = (e >> 3) & 7;
            const float* p = &aggl[vloc][(c & 1) * 32 + hi * 8];
            a = cvt8(*(const float4*)p, *(const float4*)(p + 4));
        }
#pragma unroll
        for (int cb = 0; cb < 4; cb++) {
            bf16x8 b = load_bfrag(packw, layer, 14 + c, cb, lane);
            acc[cb] = __builtin_amdgcn_mfma_f32_16x16x32_bf16(a, b, acc[cb], 0, 0, 0);
        }
    }
#pragma unroll
    for (int cb = 0; cb < 4; cb++) {
        int col = cb * 16 + r16;
        float bias = be[layer * HH + col];
#pragma unroll
        for (int r = 0; r < 4; r++) {
            size_t ofs = (size_t)(tile * 16 + hi * 4 + r) * HH + col;
            float val = acc[cb][r] + bias;
            if (LAST) out32[ofs] = val;
            else      out16[ofs] = (__bf16)val;
        }
    }
}

extern "C" void kernel_launch(void* const* d_in, const int* in_sizes, int n_in,
                              void* d_out, int out_size, void* d_ws, size_t ws_size,
                              hipStream_t stream) {
    const float* x_in    = (const float*)d_in[0];
    const float* ef_in   = (const float*)d_in[1];
    const float* Wn_self = (const float*)d_in[2];
    const float* Wn_msg  = (const float*)d_in[3];
    const float* Wn_edge = (const float*)d_in[4];
    const float* bn      = (const float*)d_in[5];
    const float* Wfc     = (const float*)d_in[6];
    const float* bfc     = (const float*)d_in[7];
    const float* We_self = (const float*)d_in[8];
    const float* We_nbr  = (const float*)d_in[9];
    const float* be      = (const float*)d_in[10];
    const int*   trg     = (const int*)d_in[12];

    size_t off = 0;
    char* w = (char*)d_ws;
    auto alloc = [&](size_t bytes) -> char* {
        char* p = w + off;
        off += (bytes + 255) & ~(size_t)255;
        return p;
    };
    int*    count  = (int*)alloc((size_t)NN * 4);
    int*    offs   = (int*)alloc((size_t)(NN + 1) * 4);
    int*    cursor = (int*)alloc((size_t)NN * 4);
    int*    inc    = (int*)alloc((size_t)EE * 4);
    int*    btot   = (int*)alloc((size_t)NB * 4);
    int*    bbase  = (int*)alloc((size_t)NB * 4);
    __bf16* packw  = (__bf16*)alloc((size_t)3 * NCG * 4 * 64 * 8 * 2);
    float*  Wse    = (float*)alloc((size_t)3 * HH * HH * 4);
    float*  Wne    = (float*)alloc((size_t)3 * HH * HH * 4);
    float*  ben    = (float*)alloc((size_t)3 * HH * 4);
    __bf16* aggxB  = (__bf16*)alloc((size_t)NN * HH * 2);
    __bf16* aggB   = (__bf16*)alloc((size_t)NN * HH * 2);  // agge0 / partB
    __bf16* AGG    = (__bf16*)alloc((size_t)NN * HH * 2);
    __bf16* xA     = (__bf16*)alloc((size_t)NN * HH * 2);
    __bf16* xB     = (__bf16*)alloc((size_t)NN * HH * 2);
    __bf16* ebA    = (__bf16*)alloc((size_t)EE * HH * 2);
    __bf16* ebB    = (__bf16*)alloc((size_t)EE * HH * 2);
    __bf16* efc16  = (__bf16*)alloc((size_t)EE * HH * 2);

    k_zero<<<(NN + 255) / 256, 256, 0, stream>>>(count);
    k_hist<<<(EE + 255) / 256, 256, 0, stream>>>(trg, count);
    k_bsum<<<NB, 256, 0, stream>>>(count, btot);
    k_bscan<<<1, 128, 0, stream>>>(btot, bbase);
    k_apply<<<NB, 256, 0, stream>>>(count, bbase, offs, cursor);
    k_fill<<<(EE + 255) / 256, 256, 0, stream>>>(trg, cursor, inc);
    k_matW<<<(2 * (2 * HH * HH + HH) + 255) / 256, 256, 0, stream>>>(
        We_self, We_nbr, be, Wn_edge, Wse, Wne, ben);
    k_pack<<<(3 * NCG * 4 * 64 * 8 + 255) / 256, 256, 0, stream>>>(
        Wn_self, Wn_msg, Wn_edge, Wfc, We_self, We_nbr, Wse, Wne, packw);

    int ntile = (NN + 15) / 16;
    int nodeblk = (ntile + 3) / 4;
    __bf16* xbuf[3] = {xA, xB, xA};
    __bf16* ebuf[2] = {ebA, ebB};

    // ---- layer 0 ----
    k_agg0<<<NN / 4, 256, 0, stream>>>(x_in, ef_in, offs, inc, aggxB, aggB);
    k_node0<<<nodeblk, 256, 0, stream>>>(x_in, aggxB, aggB, packw, bn, xbuf[0]);
    k_fc<true><<<EE / 16 / 4, 256, 0, stream>>>(ef_in, xbuf[0], trg, packw,
                                                Wfc, bfc, efc16, 0);
    k_edgeout<0, 1><<<EE / 64, 256, 0, stream>>>(efc16, offs, inc, packw, be,
                                                 ebuf[0], (float*)d_out, AGG, 0);
    // ---- layers 1..2 ----
    for (int i = 1; i < LL; i++) {
        k_aggN<<<NN / 4, 256, 0, stream>>>(xbuf[i - 1], AGG, offs, inc, aggxB, aggB);
        k_nodeL<<<nodeblk, 256, 0, stream>>>(xbuf[i - 1], aggxB, AGG, aggB, count,
                                             packw, bn, ben, xbuf[i], i);
        k_fc<false><<<EE / 16 / 4, 256, 0, stream>>>(ebuf[i - 1], xbuf[i], trg, packw,
                                                     Wfc, bfc, efc16, i);
        if (i < LL - 1)
            k_edgeout<0, 1><<<EE / 64, 256, 0, stream>>>(efc16, offs, inc, packw, be,
                                                         ebuf[i & 1], (float*)d_out, AGG, i);
        else
            k_edgeout<1, 0><<<EE / 64, 256, 0, stream>>>(efc16, offs, inc, packw, be,
                                                         ebuf[i & 1], (float*)d_out, AGG, i);
    }
}